// Round 2
// baseline (57.227 us; speedup 1.0000x reference)
//
#include <hip/hip_runtime.h>

// Cubic Hermite spline fwd (nsf cubic_spline, inverse=False), elementwise.
// Round 2: LDS-staged param loads. Global reads are fully coalesced
// (lane-consecutive float2), per-thread param access moved to LDS.
// All K=16 loops fully unrolled (static register indexing only).
// dv[] streamed as a rolling pair; h/rw recomputed to cut VGPRs.

namespace {

constexpr int K = 16;
constexpr int P2 = 2 * K + 2;     // 34 floats per element
constexpr int NF2 = P2 / 2;       // 17 float2 per element
constexpr float MBW = 0.001f;     // MIN_BIN_WIDTH
constexpr float MBH = 0.001f;     // MIN_BIN_HEIGHT

__device__ __forceinline__ float frcp(float x) { return __builtin_amdgcn_rcpf(x); }
__device__ __forceinline__ float fsgn(float v) { return (v > 0.f) ? 1.f : ((v < 0.f) ? -1.f : 0.f); }
__device__ __forceinline__ float fsigmoid(float x) { return frcp(1.f + __expf(-x)); }

__global__ __launch_bounds__(256, 4) void cubic_spline_fwd_kernel(
    const float* __restrict__ xlo,
    const float* __restrict__ xup,
    const float* __restrict__ params,
    float* __restrict__ out,
    int N)
{
    __shared__ float2 lds2[256 * NF2];   // 34,816 B

    const int tid = threadIdx.x;
    const int blockStart = blockIdx.x * 256;
    const int cnt = min(256, N - blockStart);   // elements this block

    // ---- stage params: coalesced global float2 -> linear LDS ----
    const float2* gsrc =
        reinterpret_cast<const float2*>(params) + (size_t)blockStart * NF2;
    const int nf2 = cnt * NF2;
    #pragma unroll
    for (int it = 0; it < NF2; ++it) {
        const int idx = it * 256 + tid;
        if (idx < nf2) lds2[idx] = gsrc[idx];
    }
    __syncthreads();

    if (tid >= cnt) return;
    const int i = blockStart + tid;

    const float x0 = xlo[i];
    const float x1 = xup[i];

    const float2* myp = lds2 + tid * NF2;

    // ---- softmax over widths ----
    float v[K];
    #pragma unroll
    for (int j = 0; j < 8; ++j) {
        const float2 b = myp[j];
        v[2 * j] = b.x; v[2 * j + 1] = b.y;
    }
    float mw = v[0];
    #pragma unroll
    for (int j = 1; j < K; ++j) mw = fmaxf(mw, v[j]);
    float w[K];
    float sw = 0.f;
    #pragma unroll
    for (int j = 0; j < K; ++j) { w[j] = __expf(v[j] - mw); sw += w[j]; }
    const float cw_scale = (1.0f - MBW * K) * frcp(sw);
    #pragma unroll
    for (int j = 0; j < K; ++j) w[j] = MBW + w[j] * cw_scale;

    // ---- softmax over heights -> slopes s = h/w ----
    #pragma unroll
    for (int j = 0; j < 8; ++j) {
        const float2 b = myp[8 + j];
        v[2 * j] = b.x; v[2 * j + 1] = b.y;
    }
    float mh = v[0];
    #pragma unroll
    for (int j = 1; j < K; ++j) mh = fmaxf(mh, v[j]);
    float sh = 0.f;
    #pragma unroll
    for (int j = 0; j < K; ++j) { v[j] = __expf(v[j] - mh); sh += v[j]; }
    const float ch_scale = (1.0f - MBH * K) * frcp(sh);
    float s[K];
    #pragma unroll
    for (int j = 0; j < K; ++j) {
        const float hj = MBH + v[j] * ch_scale;
        s[j] = hj * frcp(w[j]);
    }

    const float2 ud = myp[16];   // unnorm_dleft, unnorm_dright

    // ---- fused scan: stream Hermite derivatives, select bin coeffs ----
    // knots cw(j) = sum_{m<j} w[m]; x in [0,1): last bin with knot <= x wins.
    float dv_cur = fsigmoid(ud.x) * 3.f * s[0];
    float cw = 0.f, ch = 0.f;
    float a0 = 0.f, b0 = 0.f, c0 = 0.f, d0 = 0.f, l0 = 0.f;
    float a1 = 0.f, b1 = 0.f, c1 = 0.f, d1 = 0.f, l1 = 0.f;
    #pragma unroll
    for (int j = 0; j < K; ++j) {
        float dv_next;
        if (j < K - 1) {
            const float s0 = s[j], s1 = s[j + 1];
            const float w0 = w[j], w1 = w[j + 1];
            const float min1 = fminf(fabsf(s0), fabsf(s1));
            const float min2 = 0.5f * (w1 * s0 + w0 * s1) * frcp(w0 + w1);
            dv_next = fminf(min1, min2) * (fsgn(s0) + fsgn(s1));
        } else {
            dv_next = fsigmoid(ud.y) * 3.f * s[K - 1];
        }
        const float rwj = frcp(w[j]);
        const float aj = (dv_cur + dv_next - 2.f * s[j]) * (rwj * rwj);
        const float bj = (3.f * s[j] - 2.f * dv_cur - dv_next) * rwj;
        const float cj = dv_cur;
        const float dj = ch;
        const bool t0 = (j == 0) | (x0 >= cw);
        const bool t1 = (j == 0) | (x1 >= cw);
        a0 = t0 ? aj : a0; b0 = t0 ? bj : b0; c0 = t0 ? cj : c0;
        d0 = t0 ? dj : d0; l0 = t0 ? cw : l0;
        a1 = t1 ? aj : a1; b1 = t1 ? bj : b1; c1 = t1 ? cj : c1;
        d1 = t1 ? dj : d1; l1 = t1 ? cw : l1;
        cw += w[j];
        ch += s[j] * w[j];
        dv_cur = dv_next;
    }

    float t = x0 - l0;
    const float z0 = ((a0 * t + b0) * t + c0) * t + d0;
    t = x1 - l1;
    const float z1 = ((a1 * t + b1) * t + c1) * t + d1;

    out[i]     = fminf(fmaxf(z0, 0.f), 1.f);
    out[N + i] = fminf(fmaxf(z1, 0.f), 1.f);
}

}  // namespace

extern "C" void kernel_launch(void* const* d_in, const int* in_sizes, int n_in,
                              void* d_out, int out_size, void* d_ws, size_t ws_size,
                              hipStream_t stream) {
    const float* xlo    = (const float*)d_in[0];
    const float* xup    = (const float*)d_in[1];
    const float* params = (const float*)d_in[2];
    float* out = (float*)d_out;
    const int N = in_sizes[0];

    const int block = 256;
    const int grid = (N + block - 1) / block;
    cubic_spline_fwd_kernel<<<grid, block, 0, stream>>>(xlo, xup, params, out, N);
}

// Round 3
// 49.574 us; speedup vs baseline: 1.1544x; 1.1544x over previous
//
#include <hip/hip_runtime.h>

// Cubic Hermite spline fwd (nsf cubic_spline, inverse=False), elementwise.
// Round 3: 2 elements per thread. A pair's 272 B param slab is 16B-aligned,
// so params load as 17 float4 (halving strided wave-instructions vs round 1's
// 17 float2 per single element). Queries and outputs are lane-consecutive
// float2 (fully coalesced). No LDS (round-2 staging regressed).
// All K=16 loops fully unrolled — static register indexing only.

namespace {

constexpr int K = 16;
constexpr float MBW = 0.001f;     // MIN_BIN_WIDTH
constexpr float MBH = 0.001f;     // MIN_BIN_HEIGHT

__device__ __forceinline__ float frcp(float x) { return __builtin_amdgcn_rcpf(x); }
__device__ __forceinline__ float fsgn(float v) { return (v > 0.f) ? 1.f : ((v < 0.f) ? -1.f : 0.f); }
__device__ __forceinline__ float fsigmoid(float x) { return frcp(1.f + __expf(-x)); }
__device__ __forceinline__ float f4c(const float4& v, int c) {
    switch (c) { case 0: return v.x; case 1: return v.y; case 2: return v.z; default: return v.w; }
}

// Evaluate one element's spline at two query points (x_lower, x_upper).
// Returns (z_lower, z_upper), clipped to [0,1].
__device__ __forceinline__ float2 spline_eval(
    const float (&uw)[K], const float (&uh)[K],
    float udl, float udr, float x0, float x1)
{
    // softmax over widths
    float mw = uw[0];
    #pragma unroll
    for (int j = 1; j < K; ++j) mw = fmaxf(mw, uw[j]);
    float w[K];
    float sw = 0.f;
    #pragma unroll
    for (int j = 0; j < K; ++j) { w[j] = __expf(uw[j] - mw); sw += w[j]; }
    const float cw_scale = (1.0f - MBW * K) * frcp(sw);
    #pragma unroll
    for (int j = 0; j < K; ++j) w[j] = MBW + w[j] * cw_scale;

    // softmax over heights -> slopes s = h/w
    float mh = uh[0];
    #pragma unroll
    for (int j = 1; j < K; ++j) mh = fmaxf(mh, uh[j]);
    float s[K];
    float sh = 0.f;
    #pragma unroll
    for (int j = 0; j < K; ++j) { s[j] = __expf(uh[j] - mh); sh += s[j]; }
    const float ch_scale = (1.0f - MBH * K) * frcp(sh);
    #pragma unroll
    for (int j = 0; j < K; ++j) {
        const float hj = MBH + s[j] * ch_scale;
        s[j] = hj * frcp(w[j]);
    }

    // fused scan: stream Hermite knot derivatives, select bin coefficients.
    // knots cw(j) = sum_{m<j} w[m]; x in [0,1): last bin with knot <= x wins.
    float dv_cur = fsigmoid(udl) * 3.f * s[0];
    float cw = 0.f, ch = 0.f;
    float a0 = 0.f, b0 = 0.f, c0 = 0.f, d0 = 0.f, l0 = 0.f;
    float a1 = 0.f, b1 = 0.f, c1 = 0.f, d1 = 0.f, l1 = 0.f;
    #pragma unroll
    for (int j = 0; j < K; ++j) {
        float dv_next;
        if (j < K - 1) {
            const float s0 = s[j], s1 = s[j + 1];
            const float w0 = w[j], w1 = w[j + 1];
            const float min1 = fminf(fabsf(s0), fabsf(s1));
            const float min2 = 0.5f * (w1 * s0 + w0 * s1) * frcp(w0 + w1);
            dv_next = fminf(min1, min2) * (fsgn(s0) + fsgn(s1));
        } else {
            dv_next = fsigmoid(udr) * 3.f * s[K - 1];
        }
        const float rwj = frcp(w[j]);
        const float aj = (dv_cur + dv_next - 2.f * s[j]) * (rwj * rwj);
        const float bj = (3.f * s[j] - 2.f * dv_cur - dv_next) * rwj;
        const float cj = dv_cur;
        const float dj = ch;
        const bool t0 = (j == 0) | (x0 >= cw);
        const bool t1 = (j == 0) | (x1 >= cw);
        a0 = t0 ? aj : a0; b0 = t0 ? bj : b0; c0 = t0 ? cj : c0;
        d0 = t0 ? dj : d0; l0 = t0 ? cw : l0;
        a1 = t1 ? aj : a1; b1 = t1 ? bj : b1; c1 = t1 ? cj : c1;
        d1 = t1 ? dj : d1; l1 = t1 ? cw : l1;
        cw += w[j];
        ch += s[j] * w[j];
        dv_cur = dv_next;
    }

    float t = x0 - l0;
    const float z0 = ((a0 * t + b0) * t + c0) * t + d0;
    t = x1 - l1;
    const float z1 = ((a1 * t + b1) * t + c1) * t + d1;
    return make_float2(fminf(fmaxf(z0, 0.f), 1.f), fminf(fmaxf(z1, 0.f), 1.f));
}

__global__ __launch_bounds__(256) void cubic_spline_fwd_kernel(
    const float* __restrict__ xlo,
    const float* __restrict__ xup,
    const float* __restrict__ params,
    float* __restrict__ out,
    int N)
{
    const int t = blockIdx.x * 256 + threadIdx.x;
    const int i0 = 2 * t;
    if (i0 >= N) return;

    if (i0 + 1 < N) {
        // ---- pair path: 272 B param slab, 16B-aligned -> 17 float4 ----
        const float4* p4 = reinterpret_cast<const float4*>(params) + (size_t)t * 17;
        float4 f[17];
        #pragma unroll
        for (int j = 0; j < 17; ++j) f[j] = p4[j];

        const float2 xl = reinterpret_cast<const float2*>(xlo)[t];
        const float2 xu = reinterpret_cast<const float2*>(xup)[t];

        // element 0: floats [0,34)
        float uwA[K], uhA[K];
        #pragma unroll
        for (int j = 0; j < K; ++j) uwA[j] = f4c(f[j >> 2], j & 3);
        #pragma unroll
        for (int j = 0; j < K; ++j) uhA[j] = f4c(f[(16 + j) >> 2], (16 + j) & 3);
        const float2 zA = spline_eval(uwA, uhA, f[8].x, f[8].y, xl.x, xu.x);

        // element 1: floats [34,68)
        float uwB[K], uhB[K];
        #pragma unroll
        for (int j = 0; j < K; ++j) uwB[j] = f4c(f[(34 + j) >> 2], (34 + j) & 3);
        #pragma unroll
        for (int j = 0; j < K; ++j) uhB[j] = f4c(f[(50 + j) >> 2], (50 + j) & 3);
        const float2 zB = spline_eval(uwB, uhB, f[16].z, f[16].w, xl.y, xu.y);

        reinterpret_cast<float2*>(out)[t]     = make_float2(zA.x, zB.x);
        reinterpret_cast<float2*>(out + N)[t] = make_float2(zA.y, zB.y);
    } else {
        // ---- tail: single element (only when N is odd) ----
        const float2* p2 = reinterpret_cast<const float2*>(params + (size_t)i0 * 34);
        float uw[K], uh[K];
        #pragma unroll
        for (int j = 0; j < 8; ++j) {
            const float2 b = p2[j];
            uw[2 * j] = b.x; uw[2 * j + 1] = b.y;
        }
        #pragma unroll
        for (int j = 0; j < 8; ++j) {
            const float2 b = p2[8 + j];
            uh[2 * j] = b.x; uh[2 * j + 1] = b.y;
        }
        const float2 ud = p2[16];
        const float2 z = spline_eval(uw, uh, ud.x, ud.y, xlo[i0], xup[i0]);
        out[i0]     = z.x;
        out[N + i0] = z.y;
    }
}

}  // namespace

extern "C" void kernel_launch(void* const* d_in, const int* in_sizes, int n_in,
                              void* d_out, int out_size, void* d_ws, size_t ws_size,
                              hipStream_t stream) {
    const float* xlo    = (const float*)d_in[0];
    const float* xup    = (const float*)d_in[1];
    const float* params = (const float*)d_in[2];
    float* out = (float*)d_out;
    const int N = in_sizes[0];

    const int block = 256;
    const int npairs = (N + 1) / 2;
    const int grid = (npairs + block - 1) / block;
    cubic_spline_fwd_kernel<<<grid, block, 0, stream>>>(xlo, xup, params, out, N);
}

// Round 4
// 42.248 us; speedup vs baseline: 1.3545x; 1.1734x over previous
//
#include <hip/hip_runtime.h>

// Cubic Hermite spline fwd (nsf cubic_spline, inverse=False), elementwise.
// Round 4: round-1 load pattern (1 elem/thread, 17 direct float2 loads,
// issued up-front) + round-2 lean math (rolling dv pair, no h/rw arrays)
// to keep VGPR <= 128 for 4 waves/EU occupancy (launch_bounds enforced).
// All K=16 loops fully unrolled — static register indexing only.

namespace {

constexpr int K = 16;
constexpr float MBW = 0.001f;     // MIN_BIN_WIDTH
constexpr float MBH = 0.001f;     // MIN_BIN_HEIGHT

__device__ __forceinline__ float frcp(float x) { return __builtin_amdgcn_rcpf(x); }
__device__ __forceinline__ float fsgn(float v) { return (v > 0.f) ? 1.f : ((v < 0.f) ? -1.f : 0.f); }
__device__ __forceinline__ float fsigmoid(float x) { return frcp(1.f + __expf(-x)); }

__global__ __launch_bounds__(256, 4) void cubic_spline_fwd_kernel(
    const float* __restrict__ xlo,
    const float* __restrict__ xup,
    const float* __restrict__ params,
    float* __restrict__ out,
    int N)
{
    const int i = blockIdx.x * 256 + threadIdx.x;
    if (i >= N) return;

    // ---- issue all loads up-front (17 float2 params + 2 queries) ----
    const float2* p2 = reinterpret_cast<const float2*>(params) + (size_t)i * 17;
    float2 f[17];
    #pragma unroll
    for (int j = 0; j < 17; ++j) f[j] = p2[j];
    const float x0 = xlo[i];
    const float x1 = xup[i];

    // helpers to view f[] as 34 scalars with static indices
    #define PF(j) ((j) & 1 ? f[(j) >> 1].y : f[(j) >> 1].x)

    // ---- softmax over widths (f[0..7]) ----
    float mw = PF(0);
    #pragma unroll
    for (int j = 1; j < K; ++j) mw = fmaxf(mw, PF(j));
    float w[K];
    float sw = 0.f;
    #pragma unroll
    for (int j = 0; j < K; ++j) { w[j] = __expf(PF(j) - mw); sw += w[j]; }
    const float cw_scale = (1.0f - MBW * K) * frcp(sw);
    #pragma unroll
    for (int j = 0; j < K; ++j) w[j] = MBW + w[j] * cw_scale;

    // ---- softmax over heights (f[8..15]) -> slopes s = h/w ----
    float mh = PF(16);
    #pragma unroll
    for (int j = 1; j < K; ++j) mh = fmaxf(mh, PF(16 + j));
    float s[K];
    float sh = 0.f;
    #pragma unroll
    for (int j = 0; j < K; ++j) { s[j] = __expf(PF(16 + j) - mh); sh += s[j]; }
    const float ch_scale = (1.0f - MBH * K) * frcp(sh);
    #pragma unroll
    for (int j = 0; j < K; ++j) {
        const float hj = MBH + s[j] * ch_scale;
        s[j] = hj * frcp(w[j]);
    }

    const float udl = f[16].x, udr = f[16].y;
    #undef PF

    // ---- fused scan: stream Hermite knot derivatives, select bin coeffs ----
    // knots cw(j) = sum_{m<j} w[m]; x in [0,1): last bin with knot <= x wins.
    float dv_cur = fsigmoid(udl) * 3.f * s[0];
    float cw = 0.f, ch = 0.f;
    float a0 = 0.f, b0 = 0.f, c0 = 0.f, d0 = 0.f, l0 = 0.f;
    float a1 = 0.f, b1 = 0.f, c1 = 0.f, d1 = 0.f, l1 = 0.f;
    #pragma unroll
    for (int j = 0; j < K; ++j) {
        float dv_next;
        if (j < K - 1) {
            const float s0 = s[j], s1 = s[j + 1];
            const float w0 = w[j], w1 = w[j + 1];
            const float min1 = fminf(fabsf(s0), fabsf(s1));
            const float min2 = 0.5f * (w1 * s0 + w0 * s1) * frcp(w0 + w1);
            dv_next = fminf(min1, min2) * (fsgn(s0) + fsgn(s1));
        } else {
            dv_next = fsigmoid(udr) * 3.f * s[K - 1];
        }
        const float rwj = frcp(w[j]);
        const float aj = (dv_cur + dv_next - 2.f * s[j]) * (rwj * rwj);
        const float bj = (3.f * s[j] - 2.f * dv_cur - dv_next) * rwj;
        const float cj = dv_cur;
        const float dj = ch;
        const bool t0 = (j == 0) | (x0 >= cw);
        const bool t1 = (j == 0) | (x1 >= cw);
        a0 = t0 ? aj : a0; b0 = t0 ? bj : b0; c0 = t0 ? cj : c0;
        d0 = t0 ? dj : d0; l0 = t0 ? cw : l0;
        a1 = t1 ? aj : a1; b1 = t1 ? bj : b1; c1 = t1 ? cj : c1;
        d1 = t1 ? dj : d1; l1 = t1 ? cw : l1;
        cw += w[j];
        ch += s[j] * w[j];
        dv_cur = dv_next;
    }

    float t = x0 - l0;
    const float z0 = ((a0 * t + b0) * t + c0) * t + d0;
    t = x1 - l1;
    const float z1 = ((a1 * t + b1) * t + c1) * t + d1;

    out[i]     = fminf(fmaxf(z0, 0.f), 1.f);
    out[N + i] = fminf(fmaxf(z1, 0.f), 1.f);
}

}  // namespace

extern "C" void kernel_launch(void* const* d_in, const int* in_sizes, int n_in,
                              void* d_out, int out_size, void* d_ws, size_t ws_size,
                              hipStream_t stream) {
    const float* xlo    = (const float*)d_in[0];
    const float* xup    = (const float*)d_in[1];
    const float* params = (const float*)d_in[2];
    float* out = (float*)d_out;
    const int N = in_sizes[0];

    const int block = 256;
    const int grid = (N + block - 1) / block;
    cubic_spline_fwd_kernel<<<grid, block, 0, stream>>>(xlo, xup, params, out, N);
}